// Round 8
// baseline (233.105 us; speedup 1.0000x reference)
//
#include <hip/hip_runtime.h>

typedef __attribute__((ext_vector_type(8))) short v8s;   // 8 x bf16 bits
typedef __attribute__((ext_vector_type(4))) float v4f;   // MFMA accumulator

#define MFMA16(a, b, c) __builtin_amdgcn_mfma_f32_16x16x32_bf16((a), (b), (c), 0, 0, 0)
#define SCQ 0.17677669529663687f

__device__ __forceinline__ short f2bf(float f) {
    unsigned u = __float_as_uint(f);
    u += 0x7FFFu + ((u >> 16) & 1u);          // round-to-nearest-even
    return (short)(u >> 16);
}
__device__ __forceinline__ float bf2f(short s) {
    return __uint_as_float(((unsigned)(unsigned short)s) << 16);
}
__device__ __forceinline__ float bfly16(float v) {
#pragma unroll
    for (int m = 1; m < 16; m <<= 1) v += __shfl_xor(v, m);
    return v;
}

// ---------------------------------------------------------------------------
// Weight prep (unchanged layout). ws layout (shorts):
//   [0) wsp 16384 | [16384) wge | [32768) wtm | [49152) gatW+e 5120 |
//   [54272) P 8192 | [62464) u 8192 | [70656) p1 2048 | [72704) p2 512 |
//   [73216) f32 cb[64]|gamma[2]
//   [81920) x buffer: [B*3][64] bf16 (written by giman_proj)
// ---------------------------------------------------------------------------
__global__ void giman_prep(const float* __restrict__ Wsp, const float* __restrict__ Wge,
                           const float* __restrict__ Wtm, const float* __restrict__ gatW,
                           const float* __restrict__ gat_a,
                           const float* __restrict__ inw, const float* __restrict__ outw,
                           const float* __restrict__ p1w, const float* __restrict__ p2w,
                           const float* __restrict__ in_b, const float* __restrict__ out_b,
                           short* __restrict__ ws) {
    int idx = blockIdx.x * 256 + threadIdx.x;
    if (idx < 73216) {
        int j = idx & 7, l = (idx >> 3) & 63;
        int lr = l & 15, lc = ((l >> 4) << 3) + j;
        float val;
        if (idx < 49152) {
            const float* W; int off;
            if (idx < 16384)      { W = Wsp; off = idx; }
            else if (idx < 32768) { W = Wge; off = idx - 16384; }
            else                  { W = Wtm; off = idx - 32768; }
            int t = off >> 9, kk = t & 7, nb = t >> 3;
            val = W[(nb * 16 + lr) * 256 + kk * 32 + lc];
        } else if (idx < 54272) {
            int t = (idx - 49152) >> 9, kk = t & 1, nb = t >> 1;
            if (nb < 4) {
                val = gatW[(nb * 16 + lr) * 64 + kk * 32 + lc];
            } else {
                int f = kk * 32 + lc;
                val = 0.f;
                if (lr < 4) {
                    float s = 0.f;
                    for (int d = 0; d < 32; ++d)
                        s += gat_a[(lr >> 1) * 32 + d] * gatW[((lr & 1) * 32 + d) * 64 + f];
                    val = s;
                } else if (lr < 6) {
                    int h = lr - 4;
                    float s = 0.f;
                    for (int d = 0; d < 32; ++d)
                        s += inw[(32 * h + d) * 64 + f] * in_b[64 + 32 * h + d];
                    val = s * SCQ;
                } else if (lr < 8) {
                    int h = lr - 6;
                    float s = 0.f;
                    for (int d = 0; d < 32; ++d)
                        s += inw[(64 + 32 * h + d) * 64 + f] * in_b[32 * h + d];
                    val = s * SCQ;
                }
            }
        } else if (idx < 62464) {
            int t = (idx - 54272) >> 9, kk = t & 1, nbh = t >> 1;
            int h = nbh >> 2, nb = nbh & 3;
            int a = kk * 32 + lc, b = nb * 16 + lr;
            float s = 0.f;
            for (int d = 0; d < 32; ++d)
                s += inw[(32 * h + d) * 64 + a] * inw[(64 + 32 * h + d) * 64 + b];
            val = s * SCQ;
        } else if (idx < 70656) {
            int t = (idx - 62464) >> 9, kk = t & 1, nbh = t >> 1;
            int h = nbh >> 2, nb = nbh & 3;
            int r = nb * 16 + lr, c = kk * 32 + lc;
            float s = 0.f;
            for (int k = 0; k < 32; ++k)
                s += outw[r * 64 + h * 32 + k] * inw[(128 + h * 32 + k) * 64 + c];
            val = s;
        } else if (idx < 72704) {
            int t = (idx - 70656) >> 9, kk = t & 1, nb = t >> 1;
            val = p1w[(nb * 16 + lr) * 64 + kk * 32 + lc];
        } else {
            val = p2w[lr * 32 + lc];
        }
        ws[idx] = f2bf(val);
    } else if (idx < 73280) {
        int r = idx - 73216;
        float s = out_b[r];
        for (int k = 0; k < 64; ++k) s += outw[r * 64 + 128 + k] * in_b[128 + k];
        ((float*)(ws + 73216))[r] = s;
    } else if (idx < 73282) {
        int h = idx - 73280;
        float s = 0.f;
        for (int d = 0; d < 32; ++d) s += in_b[32 * h + d] * in_b[64 + 32 * h + d];
        ((float*)(ws + 73216))[64 + h] = s * SCQ;
    }
}

// ---------------------------------------------------------------------------
// K1: streaming projection, grid-stride over (group, modality) items.
// Whole 16-row x 1KB item loaded into L[16] (256B/lane in flight) before
// compute -> HBM latency hidden; ~4 waves/SIMD; blocks persistent (3 items).
// ---------------------------------------------------------------------------
__global__ __launch_bounds__(256)
void giman_proj(const float* __restrict__ spatial, const float* __restrict__ genomic,
                const float* __restrict__ temporal,
                const float* __restrict__ bsp, const float* __restrict__ bge,
                const float* __restrict__ btm,
                const short* __restrict__ wf, short* __restrict__ xg, int Btot)
{
    const int wv = threadIdx.x >> 6;
    const int lane = threadIdx.x & 63;
    const int lq = lane & 15, lg = lane >> 4;
    const int nG = Btot >> 6;
    const int nItems = 3 * nG;

    for (int it = blockIdx.x; it < nItems; it += gridDim.x) {
        const int m = it / nG;
        const int g = it - m * nG;
        const int s0 = g * 64 + wv * 16;

        const float* X = (m == 0 ? spatial : (m == 1 ? genomic : temporal))
                       + (size_t)(s0 + lq) * 256 + lg * 8;
        const float* Bm = (m == 0 ? bsp : (m == 1 ? bge : btm));
        const v8s* bwf = (const v8s*)(wf + m * 16384);

        // issue all 16 loads (256B/lane) before any use
        float4 L[16];
#pragma unroll
        for (int k = 0; k < 8; ++k) {
            L[2 * k]     = *(const float4*)(X + k * 32);
            L[2 * k + 1] = *(const float4*)(X + k * 32 + 4);
        }

        v4f acc[4];
#pragma unroll
        for (int nb = 0; nb < 4; ++nb) acc[nb] = (v4f){0.f, 0.f, 0.f, 0.f};

#pragma unroll
        for (int kk = 0; kk < 8; ++kk) {
            v8s af;
            af[0] = f2bf(L[2 * kk].x); af[1] = f2bf(L[2 * kk].y);
            af[2] = f2bf(L[2 * kk].z); af[3] = f2bf(L[2 * kk].w);
            af[4] = f2bf(L[2 * kk + 1].x); af[5] = f2bf(L[2 * kk + 1].y);
            af[6] = f2bf(L[2 * kk + 1].z); af[7] = f2bf(L[2 * kk + 1].w);
#pragma unroll
            for (int nb = 0; nb < 4; ++nb)
                acc[nb] = MFMA16(af, bwf[(nb * 8 + kk) * 64 + lane], acc[nb]);
        }

        float bb0 = Bm[lq], bb1 = Bm[16 + lq], bb2 = Bm[32 + lq], bb3 = Bm[48 + lq];
#pragma unroll
        for (int nb = 0; nb < 4; ++nb) {
            float bb = nb == 0 ? bb0 : (nb == 1 ? bb1 : (nb == 2 ? bb2 : bb3));
#pragma unroll
            for (int r = 0; r < 4; ++r) {
                float v = acc[nb][r] + bb;
                v = v > 0.f ? v : 0.f;                       // ReLU
                xg[((size_t)(s0 + 4 * lg + r) * 3 + m) * 64 + nb * 16 + lq] = f2bf(v);
            }
        }
    }
}

// ---------------------------------------------------------------------------
// K2: graph-attention + MHA + LN + predictor (unchanged from R7).
// ---------------------------------------------------------------------------
__global__ __launch_bounds__(256)
void giman_main(const float* __restrict__ adj, const short* __restrict__ wf,
                const short* __restrict__ xg,
                const float* __restrict__ ln_g, const float* __restrict__ ln_b,
                const float* __restrict__ p1b, const float* __restrict__ p2b,
                const float* __restrict__ p3w, const float* __restrict__ p3bb,
                float* __restrict__ dout, int Btot)
{
    __shared__ __align__(16) short x_lds[4][48][72];  // x; rows 0..15 become c; 16..24 z
    __shared__ __align__(16) short v_lds[4][16][72];  // v = x@P_h (head-sequential)
    __shared__ __align__(16) float a_lds[4][148];     // adj (16 samp x 9)

    const int wv   = threadIdx.x >> 6;
    const int lane = threadIdx.x & 63;
    const int lq   = lane & 15;
    const int lg   = lane >> 4;
    const int grpb = lane & 48;       // 16*lg
    const int s0   = blockIdx.x * 64 + wv * 16;
    if (s0 + 16 > Btot) return;

    short (*xw)[72] = x_lds[wv];
    short (*vtr)[72] = v_lds[wv];

    // prefetch adj
    if (lane < 36)
        *(float4*)&a_lds[wv][lane * 4] = *(const float4*)(adj + (size_t)s0 * 9 + lane * 4);

    // stage x: 48 contiguous rows (samples s0..s0+15 x 3 nodes), 6144 B / wave
    {
        const short* xsrc = xg + (size_t)s0 * 192;
#pragma unroll
        for (int i = 0; i < 6; ++i) {
            int c = lane + 64 * i;
            v8s val = *(const v8s*)(xsrc + c * 8);
            *(v8s*)&xw[c >> 3][(c & 7) * 8] = val;
        }
    }

    // ---- per-lane constants (col = nb*16+lq) ----
    const float* cbp = (const float*)(wf + 73216);
    float cbv[4], lgv[4], lbv[4];
#pragma unroll
    for (int nb = 0; nb < 4; ++nb) {
        int c = nb * 16 + lq;
        cbv[nb] = cbp[c];
        lgv[nb] = ln_g[c];
        lbv[nb] = ln_b[c];
    }
    const float gmv0 = cbp[64], gmv1 = cbp[65];
    const float inv3 = 1.f / 3.f;

    const v8s* gwf = (const v8s*)(wf + 49152);
    const v8s* pff = (const v8s*)(wf + 54272);
    const v8s* uf  = (const v8s*)(wf + 62464);

#pragma unroll 1
    for (int t = 0; t < 4; ++t) {
        // A-fragments of x (rows: 4 per sample, node clamped)
        int rn = lq & 3; rn = (rn == 3) ? 2 : rn;
        const short* xrp = xw[(t * 4 + (lq >> 2)) * 3 + rn];
        v8s xa0 = *(const v8s*)(xrp + lg * 8);
        v8s xa1 = *(const v8s*)(xrp + 32 + lg * 8);

        // ---- GAT + e/alpha/beta MFMA block; keeps eacc live for head loop ----
        float gp[4];
        v4f eacc = (v4f){0.f, 0.f, 0.f, 0.f};
        {
            v4f hacc[4];
#pragma unroll
            for (int nb = 0; nb < 4; ++nb) {
                v4f a = (v4f){0.f, 0.f, 0.f, 0.f};
                a = MFMA16(xa0, gwf[(nb * 2 + 0) * 64 + lane], a);
                a = MFMA16(xa1, gwf[(nb * 2 + 1) * 64 + lane], a);
                hacc[nb] = a;
            }
            eacc = MFMA16(xa0, gwf[8 * 64 + lane], eacc);
            eacc = MFMA16(xa1, gwf[9 * 64 + lane], eacc);

            const float* amp = &a_lds[wv][(t * 4 + lg) * 9];
            float wj0[2], wj1[2], wj2[2];
#pragma unroll
            for (int h = 0; h < 2; ++h) {
                float ei0 = __shfl(eacc[0], grpb + h);
                float ei1 = __shfl(eacc[1], grpb + h);
                float ei2 = __shfl(eacc[2], grpb + h);
                float ej0 = __shfl(eacc[0], grpb + 2 + h);
                float ej1 = __shfl(eacc[1], grpb + 2 + h);
                float ej2 = __shfl(eacc[2], grpb + 2 + h);
                float w0 = 0.f, w1 = 0.f, w2 = 0.f;
#pragma unroll
                for (int i = 0; i < 3; ++i) {
                    float eiv = i == 0 ? ei0 : (i == 1 ? ei1 : ei2);
                    float e0 = eiv + ej0; e0 = e0 > 0.f ? e0 : 0.2f * e0; if (amp[i * 3 + 0] == 0.f) e0 = -1e9f;
                    float e1 = eiv + ej1; e1 = e1 > 0.f ? e1 : 0.2f * e1; if (amp[i * 3 + 1] == 0.f) e1 = -1e9f;
                    float e2 = eiv + ej2; e2 = e2 > 0.f ? e2 : 0.2f * e2; if (amp[i * 3 + 2] == 0.f) e2 = -1e9f;
                    float mx = fmaxf(e0, fmaxf(e1, e2));
                    float q0 = __expf(e0 - mx), q1 = __expf(e1 - mx), q2 = __expf(e2 - mx);
                    float inv = 1.f / (q0 + q1 + q2);
                    w0 += q0 * inv; w1 += q1 * inv; w2 += q2 * inv;
                }
                wj0[h] = w0; wj1[h] = w1; wj2[h] = w2;
            }
#pragma unroll
            for (int nb = 0; nb < 4; ++nb) {
                int h = nb >> 1;
                gp[nb] = (wj0[h] * hacc[nb][0] + wj1[h] * hacc[nb][1] + wj2[h] * hacc[nb][2]) * inv3;
            }
        }

        // ---- y = x + cb; then per head: scores -> softmax -> u-fold ----
        float y[4][3];
#pragma unroll
        for (int nb = 0; nb < 4; ++nb)
#pragma unroll
            for (int r = 0; r < 3; ++r)
                y[nb][r] = bf2f(xw[(t * 4 + lg) * 3 + r][nb * 16 + lq]) + cbv[nb];

        const int sb = grpb + (grpb >> 2);   // 20*lg
#pragma unroll
        for (int h = 0; h < 2; ++h) {
            // v = x @ P_h -> LDS transpose -> S = v @ x^T (B-op = xa regs)
            {
                v4f va[4];
#pragma unroll
                for (int nb = 0; nb < 4; ++nb) {
                    v4f a = (v4f){0.f, 0.f, 0.f, 0.f};
                    a = MFMA16(xa0, pff[((h * 4 + nb) * 2 + 0) * 64 + lane], a);
                    a = MFMA16(xa1, pff[((h * 4 + nb) * 2 + 1) * 64 + lane], a);
                    va[nb] = a;
                }
#pragma unroll
                for (int nb = 0; nb < 4; ++nb)
#pragma unroll
                    for (int r = 0; r < 3; ++r)
                        vtr[lg * 4 + r][nb * 16 + lq] = f2bf(va[nb][r]);
            }
            v8s aq0 = *(const v8s*)&vtr[lq][lg * 8];
            v8s aq1 = *(const v8s*)&vtr[lq][32 + lg * 8];
            v4f S = (v4f){0.f, 0.f, 0.f, 0.f};
            S = MFMA16(aq0, xa0, S);
            S = MFMA16(aq1, xa1, S);

            float alh[9];
            {
                float gm = h ? gmv1 : gmv0;
                float bv0 = __shfl(eacc[0], grpb + 6 + h) + gm;
                float bv1 = __shfl(eacc[1], grpb + 6 + h) + gm;
                float bv2 = __shfl(eacc[2], grpb + 6 + h) + gm;
#pragma unroll
                for (int i = 0; i < 3; ++i) {
                    float av = __shfl(eacc[i], grpb + 4 + h);
                    float e0 = __shfl(S[i], sb + 0) + av + bv0;
                    float e1 = __shfl(S[i], sb + 1) + av + bv1;
                    float e2 = __shfl(S[i], sb + 2) + av + bv2;
                    float mx = fmaxf(e0, fmaxf(e1, e2));
                    float w0 = __expf(e0 - mx), w1 = __expf(e1 - mx), w2 = __expf(e2 - mx);
                    float inv = 1.f / (w0 + w1 + w2);
                    alh[i * 3 + 0] = w0 * inv;
                    alh[i * 3 + 1] = w1 * inv;
                    alh[i * 3 + 2] = w2 * inv;
                }
            }

            // u_h = x @ M_h^T, folded immediately into y
#pragma unroll
            for (int nb = 0; nb < 4; ++nb) {
                v4f u = (v4f){0.f, 0.f, 0.f, 0.f};
                u = MFMA16(xa0, uf[((h * 4 + nb) * 2 + 0) * 64 + lane], u);
                u = MFMA16(xa1, uf[((h * 4 + nb) * 2 + 1) * 64 + lane], u);
#pragma unroll
                for (int r = 0; r < 3; ++r)
                    y[nb][r] += alh[r * 3 + 0] * u[0] + alh[r * 3 + 1] * u[1]
                              + alh[r * 3 + 2] * u[2];
            }
        }

        // ---- LayerNorm per node row + cross-modal mean + combine with GAT ----
        float mu[3], rs[3];
#pragma unroll
        for (int r = 0; r < 3; ++r) {
            float sm = y[0][r] + y[1][r] + y[2][r] + y[3][r];
            float sq = y[0][r] * y[0][r] + y[1][r] * y[1][r]
                     + y[2][r] * y[2][r] + y[3][r] * y[3][r];
            sm = bfly16(sm); sq = bfly16(sq);
            float m_ = sm * (1.f / 64.f);
            float var = sq * (1.f / 64.f) - m_ * m_;
            mu[r] = m_;
            rs[r] = rsqrtf(var + 1e-5f);
        }
        // comb -> overlay into x rows 0..15 (row t*4+lg is dead as x by now)
#pragma unroll
        for (int nb = 0; nb < 4; ++nb) {
            float cm = (y[nb][0] - mu[0]) * rs[0] + (y[nb][1] - mu[1]) * rs[1]
                     + (y[nb][2] - mu[2]) * rs[2];
            float comb = gp[nb] + cm * inv3 * lgv[nb] + lbv[nb];
            xw[t * 4 + lg][nb * 16 + lq] = f2bf(comb);
        }
    }

    // ================= Predictor 64->32->16->2 via MFMA =================
    {
        const v8s* p1f = (const v8s*)(wf + 70656);
        const v8s* p2f = (const v8s*)(wf + 72704);
        short (*zw)[40] = (short (*)[40])(&xw[16][0]);   // rows 16.. are dead
        const short* crp = &xw[lq][0];                   // c rows 0..15
        v8s ca0 = *(const v8s*)(crp + lg * 8);
        v8s ca1 = *(const v8s*)(crp + 32 + lg * 8);
        const float pb1v0 = p1b[lq], pb1v1 = p1b[16 + lq], pb2v = p2b[lq];
        const float p3w0 = p3w[lq], p3w1 = p3w[16 + lq];
        v4f z1[2];
#pragma unroll
        for (int nb = 0; nb < 2; ++nb) {
            float bb = nb ? pb1v1 : pb1v0;
            v4f a = (v4f){bb, bb, bb, bb};
            a = MFMA16(ca0, p1f[(nb * 2 + 0) * 64 + lane], a);
            a = MFMA16(ca1, p1f[(nb * 2 + 1) * 64 + lane], a);
            z1[nb] = a;
        }
#pragma unroll
        for (int nb = 0; nb < 2; ++nb)
#pragma unroll
            for (int r = 0; r < 4; ++r) {
                float v = z1[nb][r];
                v = v > 0.f ? v : 0.f;
                zw[lg * 4 + r][nb * 16 + lq] = f2bf(v);
            }
        v8s za = *(const v8s*)(&zw[lq][0] + lg * 8);
        v4f z2 = (v4f){pb2v, pb2v, pb2v, pb2v};
        z2 = MFMA16(za, p2f[lane], z2);
        const float p3b0 = p3bb[0], p3b1 = p3bb[1];
#pragma unroll
        for (int r = 0; r < 4; ++r) {
            float v = z2[r];
            v = v > 0.f ? v : 0.f;
            float po0 = bfly16(v * p3w0);
            float po1 = bfly16(v * p3w1);
            if (lq == 0) {
                dout[s0 + lg * 4 + r] = po0 + p3b0;
                dout[Btot + s0 + lg * 4 + r] = po1 + p3b1;
            }
        }
    }
}

extern "C" void kernel_launch(void* const* d_in, const int* in_sizes, int n_in,
                              void* d_out, int out_size, void* d_ws, size_t ws_size,
                              hipStream_t stream) {
    const float* spatial  = (const float*)d_in[0];
    const float* genomic  = (const float*)d_in[1];
    const float* temporal = (const float*)d_in[2];
    const float* adj      = (const float*)d_in[3];
    const float* Wsp = (const float*)d_in[4];
    const float* bsp = (const float*)d_in[5];
    const float* Wge = (const float*)d_in[6];
    const float* bge = (const float*)d_in[7];
    const float* Wtm = (const float*)d_in[8];
    const float* btm = (const float*)d_in[9];
    const float* gatW  = (const float*)d_in[10];
    const float* gat_a = (const float*)d_in[11];
    const float* in_w  = (const float*)d_in[12];
    const float* in_b  = (const float*)d_in[13];
    const float* out_w = (const float*)d_in[14];
    const float* out_b = (const float*)d_in[15];
    const float* ln_g  = (const float*)d_in[16];
    const float* ln_b  = (const float*)d_in[17];
    const float* p1w = (const float*)d_in[18];
    const float* p1b = (const float*)d_in[19];
    const float* p2w = (const float*)d_in[20];
    const float* p2b = (const float*)d_in[21];
    const float* p3w = (const float*)d_in[22];
    const float* p3b = (const float*)d_in[23];
    float* out = (float*)d_out;
    const int Btot = in_sizes[0] / 256;

    short* wf = (short*)d_ws;
    short* xg = wf + 81920;   // x buffer: Btot*3*64 bf16

    giman_prep<<<(73282 + 255) / 256, 256, 0, stream>>>(Wsp, Wge, Wtm, gatW, gat_a,
                                                        in_w, out_w, p1w, p2w,
                                                        in_b, out_b, wf);
    giman_proj<<<2048, 256, 0, stream>>>(spatial, genomic, temporal,
                                         bsp, bge, btm, wf, xg, Btot);
    giman_main<<<Btot / 64, 256, 0, stream>>>(adj, wf, xg,
                                              ln_g, ln_b, p1b, p2b, p3w, p3b,
                                              out, Btot);
}

// Round 9
// 225.032 us; speedup vs baseline: 1.0359x; 1.0359x over previous
//
#include <hip/hip_runtime.h>

typedef __attribute__((ext_vector_type(8))) short v8s;   // 8 x bf16 bits
typedef __attribute__((ext_vector_type(4))) float v4f;   // MFMA accumulator

#define MFMA16(a, b, c) __builtin_amdgcn_mfma_f32_16x16x32_bf16((a), (b), (c), 0, 0, 0)
#define SCQ 0.17677669529663687f

__device__ __forceinline__ short f2bf(float f) {
    unsigned u = __float_as_uint(f);
    u += 0x7FFFu + ((u >> 16) & 1u);          // round-to-nearest-even
    return (short)(u >> 16);
}
__device__ __forceinline__ float bf2f(short s) {
    return __uint_as_float(((unsigned)(unsigned short)s) << 16);
}
__device__ __forceinline__ float bfly16(float v) {
#pragma unroll
    for (int m = 1; m < 16; m <<= 1) v += __shfl_xor(v, m);
    return v;
}

// ---------------------------------------------------------------------------
// Weight prep (unchanged layout). ws layout (shorts):
//   [0) wsp 16384 | [16384) wge | [32768) wtm | [49152) gatW+e 5120 |
//   [54272) P 8192 | [62464) u 8192 | [70656) p1 2048 | [72704) p2 512 |
//   [73216) f32 cb[64]|gamma[2]
//   [81920) x buffer: [B*3][64] bf16 (written by giman_proj)
// ---------------------------------------------------------------------------
__global__ void giman_prep(const float* __restrict__ Wsp, const float* __restrict__ Wge,
                           const float* __restrict__ Wtm, const float* __restrict__ gatW,
                           const float* __restrict__ gat_a,
                           const float* __restrict__ inw, const float* __restrict__ outw,
                           const float* __restrict__ p1w, const float* __restrict__ p2w,
                           const float* __restrict__ in_b, const float* __restrict__ out_b,
                           short* __restrict__ ws) {
    int idx = blockIdx.x * 256 + threadIdx.x;
    if (idx < 73216) {
        int j = idx & 7, l = (idx >> 3) & 63;
        int lr = l & 15, lc = ((l >> 4) << 3) + j;
        float val;
        if (idx < 49152) {
            const float* W; int off;
            if (idx < 16384)      { W = Wsp; off = idx; }
            else if (idx < 32768) { W = Wge; off = idx - 16384; }
            else                  { W = Wtm; off = idx - 32768; }
            int t = off >> 9, kk = t & 7, nb = t >> 3;
            val = W[(nb * 16 + lr) * 256 + kk * 32 + lc];
        } else if (idx < 54272) {
            int t = (idx - 49152) >> 9, kk = t & 1, nb = t >> 1;
            if (nb < 4) {
                val = gatW[(nb * 16 + lr) * 64 + kk * 32 + lc];
            } else {
                int f = kk * 32 + lc;
                val = 0.f;
                if (lr < 4) {
                    float s = 0.f;
                    for (int d = 0; d < 32; ++d)
                        s += gat_a[(lr >> 1) * 32 + d] * gatW[((lr & 1) * 32 + d) * 64 + f];
                    val = s;
                } else if (lr < 6) {
                    int h = lr - 4;
                    float s = 0.f;
                    for (int d = 0; d < 32; ++d)
                        s += inw[(32 * h + d) * 64 + f] * in_b[64 + 32 * h + d];
                    val = s * SCQ;
                } else if (lr < 8) {
                    int h = lr - 6;
                    float s = 0.f;
                    for (int d = 0; d < 32; ++d)
                        s += inw[(64 + 32 * h + d) * 64 + f] * in_b[32 * h + d];
                    val = s * SCQ;
                }
            }
        } else if (idx < 62464) {
            int t = (idx - 54272) >> 9, kk = t & 1, nbh = t >> 1;
            int h = nbh >> 2, nb = nbh & 3;
            int a = kk * 32 + lc, b = nb * 16 + lr;
            float s = 0.f;
            for (int d = 0; d < 32; ++d)
                s += inw[(32 * h + d) * 64 + a] * inw[(64 + 32 * h + d) * 64 + b];
            val = s * SCQ;
        } else if (idx < 70656) {
            int t = (idx - 62464) >> 9, kk = t & 1, nbh = t >> 1;
            int h = nbh >> 2, nb = nbh & 3;
            int r = nb * 16 + lr, c = kk * 32 + lc;
            float s = 0.f;
            for (int k = 0; k < 32; ++k)
                s += outw[r * 64 + h * 32 + k] * inw[(128 + h * 32 + k) * 64 + c];
            val = s;
        } else if (idx < 72704) {
            int t = (idx - 70656) >> 9, kk = t & 1, nb = t >> 1;
            val = p1w[(nb * 16 + lr) * 64 + kk * 32 + lc];
        } else {
            val = p2w[lr * 32 + lc];
        }
        ws[idx] = f2bf(val);
    } else if (idx < 73280) {
        int r = idx - 73216;
        float s = out_b[r];
        for (int k = 0; k < 64; ++k) s += outw[r * 64 + 128 + k] * in_b[128 + k];
        ((float*)(ws + 73216))[r] = s;
    } else if (idx < 73282) {
        int h = idx - 73280;
        float s = 0.f;
        for (int d = 0; d < 32; ++d) s += in_b[32 * h + d] * in_b[64 + 32 * h + d];
        ((float*)(ws + 73216))[64 + h] = s * SCQ;
    }
}

// ---------------------------------------------------------------------------
// K1: streaming projection, grid-stride over (group, modality) items.
// sched_barrier(0) pins ALL 16 dwordx4 loads (256B/lane, 16KB/wave in
// flight) before any convert/MFMA -> deep VMEM pipeline, HBM-saturating.
// ---------------------------------------------------------------------------
__global__ __launch_bounds__(256)
void giman_proj(const float* __restrict__ spatial, const float* __restrict__ genomic,
                const float* __restrict__ temporal,
                const float* __restrict__ bsp, const float* __restrict__ bge,
                const float* __restrict__ btm,
                const short* __restrict__ wf, short* __restrict__ xg, int Btot)
{
    const int wv = threadIdx.x >> 6;
    const int lane = threadIdx.x & 63;
    const int lq = lane & 15, lg = lane >> 4;
    const int nG = Btot >> 6;
    const int nItems = 3 * nG;

    for (int it = blockIdx.x; it < nItems; it += gridDim.x) {
        const int m = it / nG;
        const int g = it - m * nG;
        const int s0 = g * 64 + wv * 16;

        const float* X = (m == 0 ? spatial : (m == 1 ? genomic : temporal))
                       + (size_t)(s0 + lq) * 256 + lg * 8;
        const float* Bm = (m == 0 ? bsp : (m == 1 ? bge : btm));
        const v8s* bwf = (const v8s*)(wf + m * 16384);

        // issue ALL 16 loads; fence forbids sinking them into the compute
        float4 L[16];
#pragma unroll
        for (int k = 0; k < 8; ++k) {
            L[2 * k]     = *(const float4*)(X + k * 32);
            L[2 * k + 1] = *(const float4*)(X + k * 32 + 4);
        }
        __builtin_amdgcn_sched_barrier(0);

        v4f acc[4];
#pragma unroll
        for (int nb = 0; nb < 4; ++nb) acc[nb] = (v4f){0.f, 0.f, 0.f, 0.f};

#pragma unroll
        for (int kk = 0; kk < 8; ++kk) {
            v8s af;
            af[0] = f2bf(L[2 * kk].x); af[1] = f2bf(L[2 * kk].y);
            af[2] = f2bf(L[2 * kk].z); af[3] = f2bf(L[2 * kk].w);
            af[4] = f2bf(L[2 * kk + 1].x); af[5] = f2bf(L[2 * kk + 1].y);
            af[6] = f2bf(L[2 * kk + 1].z); af[7] = f2bf(L[2 * kk + 1].w);
#pragma unroll
            for (int nb = 0; nb < 4; ++nb)
                acc[nb] = MFMA16(af, bwf[(nb * 8 + kk) * 64 + lane], acc[nb]);
        }

        float bb0 = Bm[lq], bb1 = Bm[16 + lq], bb2 = Bm[32 + lq], bb3 = Bm[48 + lq];
#pragma unroll
        for (int nb = 0; nb < 4; ++nb) {
            float bb = nb == 0 ? bb0 : (nb == 1 ? bb1 : (nb == 2 ? bb2 : bb3));
#pragma unroll
            for (int r = 0; r < 4; ++r) {
                float v = acc[nb][r] + bb;
                v = v > 0.f ? v : 0.f;                       // ReLU
                xg[((size_t)(s0 + 4 * lg + r) * 3 + m) * 64 + nb * 16 + lq] = f2bf(v);
            }
        }
    }
}

// ---------------------------------------------------------------------------
// K2: graph-attention + MHA + LN + predictor (unchanged from R7).
// ---------------------------------------------------------------------------
__global__ __launch_bounds__(256)
void giman_main(const float* __restrict__ adj, const short* __restrict__ wf,
                const short* __restrict__ xg,
                const float* __restrict__ ln_g, const float* __restrict__ ln_b,
                const float* __restrict__ p1b, const float* __restrict__ p2b,
                const float* __restrict__ p3w, const float* __restrict__ p3bb,
                float* __restrict__ dout, int Btot)
{
    __shared__ __align__(16) short x_lds[4][48][72];  // x; rows 0..15 become c; 16..24 z
    __shared__ __align__(16) short v_lds[4][16][72];  // v = x@P_h (head-sequential)
    __shared__ __align__(16) float a_lds[4][148];     // adj (16 samp x 9)

    const int wv   = threadIdx.x >> 6;
    const int lane = threadIdx.x & 63;
    const int lq   = lane & 15;
    const int lg   = lane >> 4;
    const int grpb = lane & 48;       // 16*lg
    const int s0   = blockIdx.x * 64 + wv * 16;
    if (s0 + 16 > Btot) return;

    short (*xw)[72] = x_lds[wv];
    short (*vtr)[72] = v_lds[wv];

    // prefetch adj
    if (lane < 36)
        *(float4*)&a_lds[wv][lane * 4] = *(const float4*)(adj + (size_t)s0 * 9 + lane * 4);

    // stage x: 48 contiguous rows (samples s0..s0+15 x 3 nodes), 6144 B / wave
    {
        const short* xsrc = xg + (size_t)s0 * 192;
#pragma unroll
        for (int i = 0; i < 6; ++i) {
            int c = lane + 64 * i;
            v8s val = *(const v8s*)(xsrc + c * 8);
            *(v8s*)&xw[c >> 3][(c & 7) * 8] = val;
        }
    }

    // ---- per-lane constants (col = nb*16+lq) ----
    const float* cbp = (const float*)(wf + 73216);
    float cbv[4], lgv[4], lbv[4];
#pragma unroll
    for (int nb = 0; nb < 4; ++nb) {
        int c = nb * 16 + lq;
        cbv[nb] = cbp[c];
        lgv[nb] = ln_g[c];
        lbv[nb] = ln_b[c];
    }
    const float gmv0 = cbp[64], gmv1 = cbp[65];
    const float inv3 = 1.f / 3.f;

    const v8s* gwf = (const v8s*)(wf + 49152);
    const v8s* pff = (const v8s*)(wf + 54272);
    const v8s* uf  = (const v8s*)(wf + 62464);

#pragma unroll 1
    for (int t = 0; t < 4; ++t) {
        // A-fragments of x (rows: 4 per sample, node clamped)
        int rn = lq & 3; rn = (rn == 3) ? 2 : rn;
        const short* xrp = xw[(t * 4 + (lq >> 2)) * 3 + rn];
        v8s xa0 = *(const v8s*)(xrp + lg * 8);
        v8s xa1 = *(const v8s*)(xrp + 32 + lg * 8);

        // ---- GAT + e/alpha/beta MFMA block; keeps eacc live for head loop ----
        float gp[4];
        v4f eacc = (v4f){0.f, 0.f, 0.f, 0.f};
        {
            v4f hacc[4];
#pragma unroll
            for (int nb = 0; nb < 4; ++nb) {
                v4f a = (v4f){0.f, 0.f, 0.f, 0.f};
                a = MFMA16(xa0, gwf[(nb * 2 + 0) * 64 + lane], a);
                a = MFMA16(xa1, gwf[(nb * 2 + 1) * 64 + lane], a);
                hacc[nb] = a;
            }
            eacc = MFMA16(xa0, gwf[8 * 64 + lane], eacc);
            eacc = MFMA16(xa1, gwf[9 * 64 + lane], eacc);

            const float* amp = &a_lds[wv][(t * 4 + lg) * 9];
            float wj0[2], wj1[2], wj2[2];
#pragma unroll
            for (int h = 0; h < 2; ++h) {
                float ei0 = __shfl(eacc[0], grpb + h);
                float ei1 = __shfl(eacc[1], grpb + h);
                float ei2 = __shfl(eacc[2], grpb + h);
                float ej0 = __shfl(eacc[0], grpb + 2 + h);
                float ej1 = __shfl(eacc[1], grpb + 2 + h);
                float ej2 = __shfl(eacc[2], grpb + 2 + h);
                float w0 = 0.f, w1 = 0.f, w2 = 0.f;
#pragma unroll
                for (int i = 0; i < 3; ++i) {
                    float eiv = i == 0 ? ei0 : (i == 1 ? ei1 : ei2);
                    float e0 = eiv + ej0; e0 = e0 > 0.f ? e0 : 0.2f * e0; if (amp[i * 3 + 0] == 0.f) e0 = -1e9f;
                    float e1 = eiv + ej1; e1 = e1 > 0.f ? e1 : 0.2f * e1; if (amp[i * 3 + 1] == 0.f) e1 = -1e9f;
                    float e2 = eiv + ej2; e2 = e2 > 0.f ? e2 : 0.2f * e2; if (amp[i * 3 + 2] == 0.f) e2 = -1e9f;
                    float mx = fmaxf(e0, fmaxf(e1, e2));
                    float q0 = __expf(e0 - mx), q1 = __expf(e1 - mx), q2 = __expf(e2 - mx);
                    float inv = 1.f / (q0 + q1 + q2);
                    w0 += q0 * inv; w1 += q1 * inv; w2 += q2 * inv;
                }
                wj0[h] = w0; wj1[h] = w1; wj2[h] = w2;
            }
#pragma unroll
            for (int nb = 0; nb < 4; ++nb) {
                int h = nb >> 1;
                gp[nb] = (wj0[h] * hacc[nb][0] + wj1[h] * hacc[nb][1] + wj2[h] * hacc[nb][2]) * inv3;
            }
        }

        // ---- y = x + cb; then per head: scores -> softmax -> u-fold ----
        float y[4][3];
#pragma unroll
        for (int nb = 0; nb < 4; ++nb)
#pragma unroll
            for (int r = 0; r < 3; ++r)
                y[nb][r] = bf2f(xw[(t * 4 + lg) * 3 + r][nb * 16 + lq]) + cbv[nb];

        const int sb = grpb + (grpb >> 2);   // 20*lg
#pragma unroll
        for (int h = 0; h < 2; ++h) {
            // v = x @ P_h -> LDS transpose -> S = v @ x^T (B-op = xa regs)
            {
                v4f va[4];
#pragma unroll
                for (int nb = 0; nb < 4; ++nb) {
                    v4f a = (v4f){0.f, 0.f, 0.f, 0.f};
                    a = MFMA16(xa0, pff[((h * 4 + nb) * 2 + 0) * 64 + lane], a);
                    a = MFMA16(xa1, pff[((h * 4 + nb) * 2 + 1) * 64 + lane], a);
                    va[nb] = a;
                }
#pragma unroll
                for (int nb = 0; nb < 4; ++nb)
#pragma unroll
                    for (int r = 0; r < 3; ++r)
                        vtr[lg * 4 + r][nb * 16 + lq] = f2bf(va[nb][r]);
            }
            v8s aq0 = *(const v8s*)&vtr[lq][lg * 8];
            v8s aq1 = *(const v8s*)&vtr[lq][32 + lg * 8];
            v4f S = (v4f){0.f, 0.f, 0.f, 0.f};
            S = MFMA16(aq0, xa0, S);
            S = MFMA16(aq1, xa1, S);

            float alh[9];
            {
                float gm = h ? gmv1 : gmv0;
                float bv0 = __shfl(eacc[0], grpb + 6 + h) + gm;
                float bv1 = __shfl(eacc[1], grpb + 6 + h) + gm;
                float bv2 = __shfl(eacc[2], grpb + 6 + h) + gm;
#pragma unroll
                for (int i = 0; i < 3; ++i) {
                    float av = __shfl(eacc[i], grpb + 4 + h);
                    float e0 = __shfl(S[i], sb + 0) + av + bv0;
                    float e1 = __shfl(S[i], sb + 1) + av + bv1;
                    float e2 = __shfl(S[i], sb + 2) + av + bv2;
                    float mx = fmaxf(e0, fmaxf(e1, e2));
                    float w0 = __expf(e0 - mx), w1 = __expf(e1 - mx), w2 = __expf(e2 - mx);
                    float inv = 1.f / (w0 + w1 + w2);
                    alh[i * 3 + 0] = w0 * inv;
                    alh[i * 3 + 1] = w1 * inv;
                    alh[i * 3 + 2] = w2 * inv;
                }
            }

            // u_h = x @ M_h^T, folded immediately into y
#pragma unroll
            for (int nb = 0; nb < 4; ++nb) {
                v4f u = (v4f){0.f, 0.f, 0.f, 0.f};
                u = MFMA16(xa0, uf[((h * 4 + nb) * 2 + 0) * 64 + lane], u);
                u = MFMA16(xa1, uf[((h * 4 + nb) * 2 + 1) * 64 + lane], u);
#pragma unroll
                for (int r = 0; r < 3; ++r)
                    y[nb][r] += alh[r * 3 + 0] * u[0] + alh[r * 3 + 1] * u[1]
                              + alh[r * 3 + 2] * u[2];
            }
        }

        // ---- LayerNorm per node row + cross-modal mean + combine with GAT ----
        float mu[3], rs[3];
#pragma unroll
        for (int r = 0; r < 3; ++r) {
            float sm = y[0][r] + y[1][r] + y[2][r] + y[3][r];
            float sq = y[0][r] * y[0][r] + y[1][r] * y[1][r]
                     + y[2][r] * y[2][r] + y[3][r] * y[3][r];
            sm = bfly16(sm); sq = bfly16(sq);
            float m_ = sm * (1.f / 64.f);
            float var = sq * (1.f / 64.f) - m_ * m_;
            mu[r] = m_;
            rs[r] = rsqrtf(var + 1e-5f);
        }
        // comb -> overlay into x rows 0..15 (row t*4+lg is dead as x by now)
#pragma unroll
        for (int nb = 0; nb < 4; ++nb) {
            float cm = (y[nb][0] - mu[0]) * rs[0] + (y[nb][1] - mu[1]) * rs[1]
                     + (y[nb][2] - mu[2]) * rs[2];
            float comb = gp[nb] + cm * inv3 * lgv[nb] + lbv[nb];
            xw[t * 4 + lg][nb * 16 + lq] = f2bf(comb);
        }
    }

    // ================= Predictor 64->32->16->2 via MFMA =================
    {
        const v8s* p1f = (const v8s*)(wf + 70656);
        const v8s* p2f = (const v8s*)(wf + 72704);
        short (*zw)[40] = (short (*)[40])(&xw[16][0]);   // rows 16.. are dead
        const short* crp = &xw[lq][0];                   // c rows 0..15
        v8s ca0 = *(const v8s*)(crp + lg * 8);
        v8s ca1 = *(const v8s*)(crp + 32 + lg * 8);
        const float pb1v0 = p1b[lq], pb1v1 = p1b[16 + lq], pb2v = p2b[lq];
        const float p3w0 = p3w[lq], p3w1 = p3w[16 + lq];
        v4f z1[2];
#pragma unroll
        for (int nb = 0; nb < 2; ++nb) {
            float bb = nb ? pb1v1 : pb1v0;
            v4f a = (v4f){bb, bb, bb, bb};
            a = MFMA16(ca0, p1f[(nb * 2 + 0) * 64 + lane], a);
            a = MFMA16(ca1, p1f[(nb * 2 + 1) * 64 + lane], a);
            z1[nb] = a;
        }
#pragma unroll
        for (int nb = 0; nb < 2; ++nb)
#pragma unroll
            for (int r = 0; r < 4; ++r) {
                float v = z1[nb][r];
                v = v > 0.f ? v : 0.f;
                zw[lg * 4 + r][nb * 16 + lq] = f2bf(v);
            }
        v8s za = *(const v8s*)(&zw[lq][0] + lg * 8);
        v4f z2 = (v4f){pb2v, pb2v, pb2v, pb2v};
        z2 = MFMA16(za, p2f[lane], z2);
        const float p3b0 = p3bb[0], p3b1 = p3bb[1];
#pragma unroll
        for (int r = 0; r < 4; ++r) {
            float v = z2[r];
            v = v > 0.f ? v : 0.f;
            float po0 = bfly16(v * p3w0);
            float po1 = bfly16(v * p3w1);
            if (lq == 0) {
                dout[s0 + lg * 4 + r] = po0 + p3b0;
                dout[Btot + s0 + lg * 4 + r] = po1 + p3b1;
            }
        }
    }
}

extern "C" void kernel_launch(void* const* d_in, const int* in_sizes, int n_in,
                              void* d_out, int out_size, void* d_ws, size_t ws_size,
                              hipStream_t stream) {
    const float* spatial  = (const float*)d_in[0];
    const float* genomic  = (const float*)d_in[1];
    const float* temporal = (const float*)d_in[2];
    const float* adj      = (const float*)d_in[3];
    const float* Wsp = (const float*)d_in[4];
    const float* bsp = (const float*)d_in[5];
    const float* Wge = (const float*)d_in[6];
    const float* bge = (const float*)d_in[7];
    const float* Wtm = (const float*)d_in[8];
    const float* btm = (const float*)d_in[9];
    const float* gatW  = (const float*)d_in[10];
    const float* gat_a = (const float*)d_in[11];
    const float* in_w  = (const float*)d_in[12];
    const float* in_b  = (const float*)d_in[13];
    const float* out_w = (const float*)d_in[14];
    const float* out_b = (const float*)d_in[15];
    const float* ln_g  = (const float*)d_in[16];
    const float* ln_b  = (const float*)d_in[17];
    const float* p1w = (const float*)d_in[18];
    const float* p1b = (const float*)d_in[19];
    const float* p2w = (const float*)d_in[20];
    const float* p2b = (const float*)d_in[21];
    const float* p3w = (const float*)d_in[22];
    const float* p3b = (const float*)d_in[23];
    float* out = (float*)d_out;
    const int Btot = in_sizes[0] / 256;

    short* wf = (short*)d_ws;
    short* xg = wf + 81920;   // x buffer: Btot*3*64 bf16

    giman_prep<<<(73282 + 255) / 256, 256, 0, stream>>>(Wsp, Wge, Wtm, gatW, gat_a,
                                                        in_w, out_w, p1w, p2w,
                                                        in_b, out_b, wf);
    giman_proj<<<2048, 256, 0, stream>>>(spatial, genomic, temporal,
                                         bsp, bge, btm, wf, xg, Btot);
    giman_main<<<Btot / 64, 256, 0, stream>>>(adj, wf, xg,
                                              ln_g, ln_b, p1b, p2b, p3w, p3b,
                                              out, Btot);
}

// Round 10
// 221.318 us; speedup vs baseline: 1.0533x; 1.0168x over previous
//
#include <hip/hip_runtime.h>

typedef __attribute__((ext_vector_type(8))) short v8s;   // 8 x bf16 bits
typedef __attribute__((ext_vector_type(4))) float v4f;   // MFMA accumulator

#define MFMA16(a, b, c) __builtin_amdgcn_mfma_f32_16x16x32_bf16((a), (b), (c), 0, 0, 0)
#define SCQ 0.17677669529663687f

__device__ __forceinline__ short f2bf(float f) {
    unsigned u = __float_as_uint(f);
    u += 0x7FFFu + ((u >> 16) & 1u);          // round-to-nearest-even
    return (short)(u >> 16);
}
__device__ __forceinline__ float bf2f(short s) {
    return __uint_as_float(((unsigned)(unsigned short)s) << 16);
}
__device__ __forceinline__ float bfly16(float v) {
#pragma unroll
    for (int m = 1; m < 16; m <<= 1) v += __shfl_xor(v, m);
    return v;
}
__device__ __forceinline__ void gload16(const float* g, float* l) {
    __builtin_amdgcn_global_load_lds((const __attribute__((address_space(1))) void*)g,
                                     (__attribute__((address_space(3))) void*)l, 16, 0, 0);
}

// ---------------------------------------------------------------------------
// Weight prep (unchanged layout). ws layout (shorts):
//   [0) wsp 16384 | [16384) wge | [32768) wtm | [49152) gatW+e 5120 |
//   [54272) P 8192 | [62464) u 8192 | [70656) p1 2048 | [72704) p2 512 |
//   [73216) f32 cb[64]|gamma[2]
//   [81920) x buffer: [B*3][64] bf16 (written by giman_proj)
// ---------------------------------------------------------------------------
__global__ void giman_prep(const float* __restrict__ Wsp, const float* __restrict__ Wge,
                           const float* __restrict__ Wtm, const float* __restrict__ gatW,
                           const float* __restrict__ gat_a,
                           const float* __restrict__ inw, const float* __restrict__ outw,
                           const float* __restrict__ p1w, const float* __restrict__ p2w,
                           const float* __restrict__ in_b, const float* __restrict__ out_b,
                           short* __restrict__ ws) {
    int idx = blockIdx.x * 256 + threadIdx.x;
    if (idx < 73216) {
        int j = idx & 7, l = (idx >> 3) & 63;
        int lr = l & 15, lc = ((l >> 4) << 3) + j;
        float val;
        if (idx < 49152) {
            const float* W; int off;
            if (idx < 16384)      { W = Wsp; off = idx; }
            else if (idx < 32768) { W = Wge; off = idx - 16384; }
            else                  { W = Wtm; off = idx - 32768; }
            int t = off >> 9, kk = t & 7, nb = t >> 3;
            val = W[(nb * 16 + lr) * 256 + kk * 32 + lc];
        } else if (idx < 54272) {
            int t = (idx - 49152) >> 9, kk = t & 1, nb = t >> 1;
            if (nb < 4) {
                val = gatW[(nb * 16 + lr) * 64 + kk * 32 + lc];
            } else {
                int f = kk * 32 + lc;
                val = 0.f;
                if (lr < 4) {
                    float s = 0.f;
                    for (int d = 0; d < 32; ++d)
                        s += gat_a[(lr >> 1) * 32 + d] * gatW[((lr & 1) * 32 + d) * 64 + f];
                    val = s;
                } else if (lr < 6) {
                    int h = lr - 4;
                    float s = 0.f;
                    for (int d = 0; d < 32; ++d)
                        s += inw[(32 * h + d) * 64 + f] * in_b[64 + 32 * h + d];
                    val = s * SCQ;
                } else if (lr < 8) {
                    int h = lr - 6;
                    float s = 0.f;
                    for (int d = 0; d < 32; ++d)
                        s += inw[(64 + 32 * h + d) * 64 + f] * in_b[32 * h + d];
                    val = s * SCQ;
                }
            }
        } else if (idx < 62464) {
            int t = (idx - 54272) >> 9, kk = t & 1, nbh = t >> 1;
            int h = nbh >> 2, nb = nbh & 3;
            int a = kk * 32 + lc, b = nb * 16 + lr;
            float s = 0.f;
            for (int d = 0; d < 32; ++d)
                s += inw[(32 * h + d) * 64 + a] * inw[(64 + 32 * h + d) * 64 + b];
            val = s * SCQ;
        } else if (idx < 70656) {
            int t = (idx - 62464) >> 9, kk = t & 1, nbh = t >> 1;
            int h = nbh >> 2, nb = nbh & 3;
            int r = nb * 16 + lr, c = kk * 32 + lc;
            float s = 0.f;
            for (int k = 0; k < 32; ++k)
                s += outw[r * 64 + h * 32 + k] * inw[(128 + h * 32 + k) * 64 + c];
            val = s;
        } else if (idx < 72704) {
            int t = (idx - 70656) >> 9, kk = t & 1, nb = t >> 1;
            val = p1w[(nb * 16 + lr) * 64 + kk * 32 + lc];
        } else {
            val = p2w[lr * 32 + lc];
        }
        ws[idx] = f2bf(val);
    } else if (idx < 73280) {
        int r = idx - 73216;
        float s = out_b[r];
        for (int k = 0; k < 64; ++k) s += outw[r * 64 + 128 + k] * in_b[128 + k];
        ((float*)(ws + 73216))[r] = s;
    } else if (idx < 73282) {
        int h = idx - 73280;
        float s = 0.f;
        for (int d = 0; d < 32; ++d) s += in_b[32 * h + d] * in_b[64 + 32 * h + d];
        ((float*)(ws + 73216))[64 + h] = s * SCQ;
    }
}

// ---------------------------------------------------------------------------
// K1: streaming projection via global_load_lds staging.
// Item = 32 samples x 1 modality = 32KB contiguous. LDS [32][260] f32
// (+4 pad/row -> conflict-free ds_read_b128; per-row staging instrs keep
// the linear-dest rule). 4 blocks/CU stagger stage-drain vs compute.
// Wave roles: (wv&1) = sample half, (wv>>1) = output nb-pair.
// ---------------------------------------------------------------------------
__global__ __launch_bounds__(256)
void giman_proj(const float* __restrict__ spatial, const float* __restrict__ genomic,
                const float* __restrict__ temporal,
                const float* __restrict__ bsp, const float* __restrict__ bge,
                const float* __restrict__ btm,
                const short* __restrict__ wf, short* __restrict__ xg, int Btot)
{
    __shared__ __align__(16) float xs[32][260];

    const int wv = threadIdx.x >> 6;
    const int lane = threadIdx.x & 63;
    const int lq = lane & 15, lg = lane >> 4;
    const int half = wv & 1;
    const int nbp  = wv >> 1;
    const int nG = Btot >> 5;          // 32-sample groups per modality
    const int nItems = 3 * nG;

    for (int it = blockIdx.x; it < nItems; it += gridDim.x) {
        const int m = it / nG;
        const int g = it - m * nG;
        const int s0 = g * 32;

        const float* Xm = (m == 0 ? spatial : (m == 1 ? genomic : temporal));
        const float* src = Xm + (size_t)s0 * 256;
        const float* Bm = (m == 0 ? bsp : (m == 1 ? bge : btm));
        const v8s* bwf = (const v8s*)(wf + m * 16384);

        // stage 32 rows; wave wv stages rows 8*wv .. 8*wv+7 (1KB each)
#pragma unroll
        for (int i = 0; i < 8; ++i) {
            int row = wv * 8 + i;
            gload16(src + row * 256 + lane * 4, &xs[row][0]);
        }
        __syncthreads();

        v4f acc0 = (v4f){0.f, 0.f, 0.f, 0.f};
        v4f acc1 = (v4f){0.f, 0.f, 0.f, 0.f};
#pragma unroll
        for (int kk = 0; kk < 8; ++kk) {
            const float* rp = &xs[half * 16 + lq][kk * 32 + lg * 8];
            float4 u = *(const float4*)rp;
            float4 v = *(const float4*)(rp + 4);
            v8s af;
            af[0] = f2bf(u.x); af[1] = f2bf(u.y); af[2] = f2bf(u.z); af[3] = f2bf(u.w);
            af[4] = f2bf(v.x); af[5] = f2bf(v.y); af[6] = f2bf(v.z); af[7] = f2bf(v.w);
            acc0 = MFMA16(af, bwf[((nbp * 2 + 0) * 8 + kk) * 64 + lane], acc0);
            acc1 = MFMA16(af, bwf[((nbp * 2 + 1) * 8 + kk) * 64 + lane], acc1);
        }

        float bb0 = Bm[nbp * 32 + lq], bb1 = Bm[nbp * 32 + 16 + lq];
#pragma unroll
        for (int r = 0; r < 4; ++r) {
            int row = s0 + half * 16 + 4 * lg + r;
            size_t base = ((size_t)row * 3 + m) * 64 + nbp * 32 + lq;
            float v0 = acc0[r] + bb0; v0 = v0 > 0.f ? v0 : 0.f;
            float v1 = acc1[r] + bb1; v1 = v1 > 0.f ? v1 : 0.f;
            xg[base] = f2bf(v0);
            xg[base + 16] = f2bf(v1);
        }
        __syncthreads();
    }
}

// ---------------------------------------------------------------------------
// K2: graph-attention + MHA + LN + predictor (unchanged from R7).
// ---------------------------------------------------------------------------
__global__ __launch_bounds__(256)
void giman_main(const float* __restrict__ adj, const short* __restrict__ wf,
                const short* __restrict__ xg,
                const float* __restrict__ ln_g, const float* __restrict__ ln_b,
                const float* __restrict__ p1b, const float* __restrict__ p2b,
                const float* __restrict__ p3w, const float* __restrict__ p3bb,
                float* __restrict__ dout, int Btot)
{
    __shared__ __align__(16) short x_lds[4][48][72];  // x; rows 0..15 become c; 16..24 z
    __shared__ __align__(16) short v_lds[4][16][72];  // v = x@P_h (head-sequential)
    __shared__ __align__(16) float a_lds[4][148];     // adj (16 samp x 9)

    const int wv   = threadIdx.x >> 6;
    const int lane = threadIdx.x & 63;
    const int lq   = lane & 15;
    const int lg   = lane >> 4;
    const int grpb = lane & 48;       // 16*lg
    const int s0   = blockIdx.x * 64 + wv * 16;
    if (s0 + 16 > Btot) return;

    short (*xw)[72] = x_lds[wv];
    short (*vtr)[72] = v_lds[wv];

    // prefetch adj
    if (lane < 36)
        *(float4*)&a_lds[wv][lane * 4] = *(const float4*)(adj + (size_t)s0 * 9 + lane * 4);

    // stage x: 48 contiguous rows (samples s0..s0+15 x 3 nodes), 6144 B / wave
    {
        const short* xsrc = xg + (size_t)s0 * 192;
#pragma unroll
        for (int i = 0; i < 6; ++i) {
            int c = lane + 64 * i;
            v8s val = *(const v8s*)(xsrc + c * 8);
            *(v8s*)&xw[c >> 3][(c & 7) * 8] = val;
        }
    }

    // ---- per-lane constants (col = nb*16+lq) ----
    const float* cbp = (const float*)(wf + 73216);
    float cbv[4], lgv[4], lbv[4];
#pragma unroll
    for (int nb = 0; nb < 4; ++nb) {
        int c = nb * 16 + lq;
        cbv[nb] = cbp[c];
        lgv[nb] = ln_g[c];
        lbv[nb] = ln_b[c];
    }
    const float gmv0 = cbp[64], gmv1 = cbp[65];
    const float inv3 = 1.f / 3.f;

    const v8s* gwf = (const v8s*)(wf + 49152);
    const v8s* pff = (const v8s*)(wf + 54272);
    const v8s* uf  = (const v8s*)(wf + 62464);

#pragma unroll 1
    for (int t = 0; t < 4; ++t) {
        // A-fragments of x (rows: 4 per sample, node clamped)
        int rn = lq & 3; rn = (rn == 3) ? 2 : rn;
        const short* xrp = xw[(t * 4 + (lq >> 2)) * 3 + rn];
        v8s xa0 = *(const v8s*)(xrp + lg * 8);
        v8s xa1 = *(const v8s*)(xrp + 32 + lg * 8);

        // ---- GAT + e/alpha/beta MFMA block; keeps eacc live for head loop ----
        float gp[4];
        v4f eacc = (v4f){0.f, 0.f, 0.f, 0.f};
        {
            v4f hacc[4];
#pragma unroll
            for (int nb = 0; nb < 4; ++nb) {
                v4f a = (v4f){0.f, 0.f, 0.f, 0.f};
                a = MFMA16(xa0, gwf[(nb * 2 + 0) * 64 + lane], a);
                a = MFMA16(xa1, gwf[(nb * 2 + 1) * 64 + lane], a);
                hacc[nb] = a;
            }
            eacc = MFMA16(xa0, gwf[8 * 64 + lane], eacc);
            eacc = MFMA16(xa1, gwf[9 * 64 + lane], eacc);

            const float* amp = &a_lds[wv][(t * 4 + lg) * 9];
            float wj0[2], wj1[2], wj2[2];
#pragma unroll
            for (int h = 0; h < 2; ++h) {
                float ei0 = __shfl(eacc[0], grpb + h);
                float ei1 = __shfl(eacc[1], grpb + h);
                float ei2 = __shfl(eacc[2], grpb + h);
                float ej0 = __shfl(eacc[0], grpb + 2 + h);
                float ej1 = __shfl(eacc[1], grpb + 2 + h);
                float ej2 = __shfl(eacc[2], grpb + 2 + h);
                float w0 = 0.f, w1 = 0.f, w2 = 0.f;
#pragma unroll
                for (int i = 0; i < 3; ++i) {
                    float eiv = i == 0 ? ei0 : (i == 1 ? ei1 : ei2);
                    float e0 = eiv + ej0; e0 = e0 > 0.f ? e0 : 0.2f * e0; if (amp[i * 3 + 0] == 0.f) e0 = -1e9f;
                    float e1 = eiv + ej1; e1 = e1 > 0.f ? e1 : 0.2f * e1; if (amp[i * 3 + 1] == 0.f) e1 = -1e9f;
                    float e2 = eiv + ej2; e2 = e2 > 0.f ? e2 : 0.2f * e2; if (amp[i * 3 + 2] == 0.f) e2 = -1e9f;
                    float mx = fmaxf(e0, fmaxf(e1, e2));
                    float q0 = __expf(e0 - mx), q1 = __expf(e1 - mx), q2 = __expf(e2 - mx);
                    float inv = 1.f / (q0 + q1 + q2);
                    w0 += q0 * inv; w1 += q1 * inv; w2 += q2 * inv;
                }
                wj0[h] = w0; wj1[h] = w1; wj2[h] = w2;
            }
#pragma unroll
            for (int nb = 0; nb < 4; ++nb) {
                int h = nb >> 1;
                gp[nb] = (wj0[h] * hacc[nb][0] + wj1[h] * hacc[nb][1] + wj2[h] * hacc[nb][2]) * inv3;
            }
        }

        // ---- y = x + cb; then per head: scores -> softmax -> u-fold ----
        float y[4][3];
#pragma unroll
        for (int nb = 0; nb < 4; ++nb)
#pragma unroll
            for (int r = 0; r < 3; ++r)
                y[nb][r] = bf2f(xw[(t * 4 + lg) * 3 + r][nb * 16 + lq]) + cbv[nb];

        const int sb = grpb + (grpb >> 2);   // 20*lg
#pragma unroll
        for (int h = 0; h < 2; ++h) {
            // v = x @ P_h -> LDS transpose -> S = v @ x^T (B-op = xa regs)
            {
                v4f va[4];
#pragma unroll
                for (int nb = 0; nb < 4; ++nb) {
                    v4f a = (v4f){0.f, 0.f, 0.f, 0.f};
                    a = MFMA16(xa0, pff[((h * 4 + nb) * 2 + 0) * 64 + lane], a);
                    a = MFMA16(xa1, pff[((h * 4 + nb) * 2 + 1) * 64 + lane], a);
                    va[nb] = a;
                }
#pragma unroll
                for (int nb = 0; nb < 4; ++nb)
#pragma unroll
                    for (int r = 0; r < 3; ++r)
                        vtr[lg * 4 + r][nb * 16 + lq] = f2bf(va[nb][r]);
            }
            v8s aq0 = *(const v8s*)&vtr[lq][lg * 8];
            v8s aq1 = *(const v8s*)&vtr[lq][32 + lg * 8];
            v4f S = (v4f){0.f, 0.f, 0.f, 0.f};
            S = MFMA16(aq0, xa0, S);
            S = MFMA16(aq1, xa1, S);

            float alh[9];
            {
                float gm = h ? gmv1 : gmv0;
                float bv0 = __shfl(eacc[0], grpb + 6 + h) + gm;
                float bv1 = __shfl(eacc[1], grpb + 6 + h) + gm;
                float bv2 = __shfl(eacc[2], grpb + 6 + h) + gm;
#pragma unroll
                for (int i = 0; i < 3; ++i) {
                    float av = __shfl(eacc[i], grpb + 4 + h);
                    float e0 = __shfl(S[i], sb + 0) + av + bv0;
                    float e1 = __shfl(S[i], sb + 1) + av + bv1;
                    float e2 = __shfl(S[i], sb + 2) + av + bv2;
                    float mx = fmaxf(e0, fmaxf(e1, e2));
                    float w0 = __expf(e0 - mx), w1 = __expf(e1 - mx), w2 = __expf(e2 - mx);
                    float inv = 1.f / (w0 + w1 + w2);
                    alh[i * 3 + 0] = w0 * inv;
                    alh[i * 3 + 1] = w1 * inv;
                    alh[i * 3 + 2] = w2 * inv;
                }
            }

            // u_h = x @ M_h^T, folded immediately into y
#pragma unroll
            for (int nb = 0; nb < 4; ++nb) {
                v4f u = (v4f){0.f, 0.f, 0.f, 0.f};
                u = MFMA16(xa0, uf[((h * 4 + nb) * 2 + 0) * 64 + lane], u);
                u = MFMA16(xa1, uf[((h * 4 + nb) * 2 + 1) * 64 + lane], u);
#pragma unroll
                for (int r = 0; r < 3; ++r)
                    y[nb][r] += alh[r * 3 + 0] * u[0] + alh[r * 3 + 1] * u[1]
                              + alh[r * 3 + 2] * u[2];
            }
        }

        // ---- LayerNorm per node row + cross-modal mean + combine with GAT ----
        float mu[3], rs[3];
#pragma unroll
        for (int r = 0; r < 3; ++r) {
            float sm = y[0][r] + y[1][r] + y[2][r] + y[3][r];
            float sq = y[0][r] * y[0][r] + y[1][r] * y[1][r]
                     + y[2][r] * y[2][r] + y[3][r] * y[3][r];
            sm = bfly16(sm); sq = bfly16(sq);
            float m_ = sm * (1.f / 64.f);
            float var = sq * (1.f / 64.f) - m_ * m_;
            mu[r] = m_;
            rs[r] = rsqrtf(var + 1e-5f);
        }
        // comb -> overlay into x rows 0..15 (row t*4+lg is dead as x by now)
#pragma unroll
        for (int nb = 0; nb < 4; ++nb) {
            float cm = (y[nb][0] - mu[0]) * rs[0] + (y[nb][1] - mu[1]) * rs[1]
                     + (y[nb][2] - mu[2]) * rs[2];
            float comb = gp[nb] + cm * inv3 * lgv[nb] + lbv[nb];
            xw[t * 4 + lg][nb * 16 + lq] = f2bf(comb);
        }
    }

    // ================= Predictor 64->32->16->2 via MFMA =================
    {
        const v8s* p1f = (const v8s*)(wf + 70656);
        const v8s* p2f = (const v8s*)(wf + 72704);
        short (*zw)[40] = (short (*)[40])(&xw[16][0]);   // rows 16.. are dead
        const short* crp = &xw[lq][0];                   // c rows 0..15
        v8s ca0 = *(const v8s*)(crp + lg * 8);
        v8s ca1 = *(const v8s*)(crp + 32 + lg * 8);
        const float pb1v0 = p1b[lq], pb1v1 = p1b[16 + lq], pb2v = p2b[lq];
        const float p3w0 = p3w[lq], p3w1 = p3w[16 + lq];
        v4f z1[2];
#pragma unroll
        for (int nb = 0; nb < 2; ++nb) {
            float bb = nb ? pb1v1 : pb1v0;
            v4f a = (v4f){bb, bb, bb, bb};
            a = MFMA16(ca0, p1f[(nb * 2 + 0) * 64 + lane], a);
            a = MFMA16(ca1, p1f[(nb * 2 + 1) * 64 + lane], a);
            z1[nb] = a;
        }
#pragma unroll
        for (int nb = 0; nb < 2; ++nb)
#pragma unroll
            for (int r = 0; r < 4; ++r) {
                float v = z1[nb][r];
                v = v > 0.f ? v : 0.f;
                zw[lg * 4 + r][nb * 16 + lq] = f2bf(v);
            }
        v8s za = *(const v8s*)(&zw[lq][0] + lg * 8);
        v4f z2 = (v4f){pb2v, pb2v, pb2v, pb2v};
        z2 = MFMA16(za, p2f[lane], z2);
        const float p3b0 = p3bb[0], p3b1 = p3bb[1];
#pragma unroll
        for (int r = 0; r < 4; ++r) {
            float v = z2[r];
            v = v > 0.f ? v : 0.f;
            float po0 = bfly16(v * p3w0);
            float po1 = bfly16(v * p3w1);
            if (lq == 0) {
                dout[s0 + lg * 4 + r] = po0 + p3b0;
                dout[Btot + s0 + lg * 4 + r] = po1 + p3b1;
            }
        }
    }
}

extern "C" void kernel_launch(void* const* d_in, const int* in_sizes, int n_in,
                              void* d_out, int out_size, void* d_ws, size_t ws_size,
                              hipStream_t stream) {
    const float* spatial  = (const float*)d_in[0];
    const float* genomic  = (const float*)d_in[1];
    const float* temporal = (const float*)d_in[2];
    const float* adj      = (const float*)d_in[3];
    const float* Wsp = (const float*)d_in[4];
    const float* bsp = (const float*)d_in[5];
    const float* Wge = (const float*)d_in[6];
    const float* bge = (const float*)d_in[7];
    const float* Wtm = (const float*)d_in[8];
    const float* btm = (const float*)d_in[9];
    const float* gatW  = (const float*)d_in[10];
    const float* gat_a = (const float*)d_in[11];
    const float* in_w  = (const float*)d_in[12];
    const float* in_b  = (const float*)d_in[13];
    const float* out_w = (const float*)d_in[14];
    const float* out_b = (const float*)d_in[15];
    const float* ln_g  = (const float*)d_in[16];
    const float* ln_b  = (const float*)d_in[17];
    const float* p1w = (const float*)d_in[18];
    const float* p1b = (const float*)d_in[19];
    const float* p2w = (const float*)d_in[20];
    const float* p2b = (const float*)d_in[21];
    const float* p3w = (const float*)d_in[22];
    const float* p3b = (const float*)d_in[23];
    float* out = (float*)d_out;
    const int Btot = in_sizes[0] / 256;

    short* wf = (short*)d_ws;
    short* xg = wf + 81920;   // x buffer: Btot*3*64 bf16

    giman_prep<<<(73282 + 255) / 256, 256, 0, stream>>>(Wsp, Wge, Wtm, gatW, gat_a,
                                                        in_w, out_w, p1w, p2w,
                                                        in_b, out_b, wf);
    giman_proj<<<1024, 256, 0, stream>>>(spatial, genomic, temporal,
                                         bsp, bge, btm, wf, xg, Btot);
    giman_main<<<Btot / 64, 256, 0, stream>>>(adj, wf, xg,
                                              ln_g, ln_b, p1b, p2b, p3w, p3b,
                                              out, Btot);
}